// Round 3
// baseline (44.005 us; speedup 1.0000x reference)
//
#include <hip/hip_runtime.h>
#include <math.h>

#define IN_FEAT 4096
#define OUT_FEAT 2048
#define NUM_KNOTS 10
#define DEGREE 3
#define N_BASIS 6            // NUM_KNOTS - DEGREE - 1

#define TI 256               // threads per block (main kernel)
#define OPT 2                // outputs per thread
#define IBLK (TI * OPT)      // 512 outputs per block
#define JCHUNK 16            // input rows per chunk
#define NCHUNK (IN_FEAT / JCHUNK)   // 256

// ---------------- fused: basis (per chunk) + partial dot ----------------
__global__ __launch_bounds__(TI) void kan_partial_kernel(
    const float* __restrict__ coeffs,    // [IN][OUT][N_BASIS]
    const float* __restrict__ bw,        // [IN][OUT]
    const float* __restrict__ x,         // [IN]
    float* __restrict__ partials) {      // [NCHUNK][OUT]
    __shared__ float4 w4[JCHUNK][2];     // {B0..B3},{B4,B5,silu,pad} per j
    const int tid = threadIdx.x;
    const int j0 = blockIdx.y * JCHUNK;

    if (tid < JCHUNK) {
        float xv = x[j0 + tid];
        float t[NUM_KNOTS];
#pragma unroll
        for (int m = 0; m < NUM_KNOTS; ++m)
            t[m] = -1.0f + (2.0f / 9.0f) * (float)m;
        float N[NUM_KNOTS - 1];
#pragma unroll
        for (int m = 0; m < NUM_KNOTS - 1; ++m)
            N[m] = (xv >= t[m] && xv < t[m + 1]) ? 1.0f : 0.0f;
#pragma unroll
        for (int d = 1; d <= DEGREE; ++d) {
#pragma unroll
            for (int m = 0; m + d < NUM_KNOTS - 1; ++m) {
                float ld = t[m + d] - t[m];
                float rd = t[m + d + 1] - t[m + 1];
                float lv = (ld > 0.0f) ? (xv - t[m]) / ld * N[m] : 0.0f;
                float rv = (rd > 0.0f) ? (t[m + d + 1] - xv) / rd * N[m + 1] : 0.0f;
                N[m] = lv + rv;
            }
        }
        float* wp = (float*)&w4[tid][0];
#pragma unroll
        for (int k = 0; k < N_BASIS; ++k) wp[k] = N[k];
        wp[6] = xv / (1.0f + expf(-xv));   // silu
        wp[7] = 0.0f;
    }
    __syncthreads();

    const int i0 = blockIdx.x * IBLK + tid * OPT;     // first of this thread's 2 outputs
    const float4* cp = (const float4*)(coeffs + ((size_t)j0 * OUT_FEAT + i0) * N_BASIS);
    const float2* bp = (const float2*)(bw + (size_t)j0 * OUT_FEAT + i0);

    float acc0 = 0.0f, acc1 = 0.0f;
#pragma unroll 4
    for (int j = 0; j < JCHUNK; ++j) {
        float4 a = cp[0];                 // i0:   c0 c1 c2 c3
        float4 b = cp[1];                 //       c4 c5 | i0+1: c0 c1
        float4 c = cp[2];                 //       c2 c3 c4 c5
        float2 bb = bp[0];
        float4 w0 = w4[j][0];             // B0..B3   (LDS broadcast)
        float4 w1 = w4[j][1];             // B4,B5,silu,pad
        acc0 += a.x * w0.x + a.y * w0.y + a.z * w0.z + a.w * w0.w
              + b.x * w1.x + b.y * w1.y + bb.x * w1.z;
        acc1 += b.z * w0.x + b.w * w0.y + c.x * w0.z + c.y * w0.w
              + c.z * w1.x + c.w * w1.y + bb.y * w1.z;
        cp += OUT_FEAT * N_BASIS / 4;
        bp += OUT_FEAT / 2;
    }
    float2* pp = (float2*)(partials + (size_t)blockIdx.y * OUT_FEAT + i0);
    pp[0] = make_float2(acc0, acc1);
}

// ---------------- single-stage deterministic reduce ----------------
// 32 blocks x 256 threads. Block b owns outputs [b*64, b*64+64).
// Wave w (0..3) sums chunks [w*64, w*64+64) for its lane's output;
// fixed-order LDS combine of the 4 wave-partials -> deterministic.
__global__ __launch_bounds__(256) void kan_reduce_kernel(
    const float* __restrict__ partials,  // [NCHUNK][OUT]
    float* __restrict__ out) {           // [OUT]
    __shared__ float sm[4][64];
    const int tid = threadIdx.x;
    const int w = tid >> 6;              // wave id 0..3
    const int l = tid & 63;              // lane id
    const int i = blockIdx.x * 64 + l;   // output column (contiguous across lanes)

    float acc = 0.0f;
    const float* p = partials + (size_t)(w * (NCHUNK / 4)) * OUT_FEAT + i;
#pragma unroll 8
    for (int c = 0; c < NCHUNK / 4; ++c) {
        acc += p[0];
        p += OUT_FEAT;
    }
    sm[w][l] = acc;
    __syncthreads();
    if (tid < 64) {
        out[blockIdx.x * 64 + tid] =
            sm[0][tid] + sm[1][tid] + sm[2][tid] + sm[3][tid];
    }
}

extern "C" void kernel_launch(void* const* d_in, const int* in_sizes, int n_in,
                              void* d_out, int out_size, void* d_ws, size_t ws_size,
                              hipStream_t stream) {
    const float* x      = (const float*)d_in[0];   // [4096]
    const float* coeffs = (const float*)d_in[1];   // [4096][2048][6]
    const float* bw     = (const float*)d_in[2];   // [4096][2048]
    float* out = (float*)d_out;                    // [2048] fp32

    float* partials = (float*)d_ws;                // NCHUNK*2048 floats (2 MB)

    dim3 grid(OUT_FEAT / IBLK, NCHUNK);            // (4, 256) = 1024 blocks
    kan_partial_kernel<<<grid, TI, 0, stream>>>(coeffs, bw, x, partials);

    kan_reduce_kernel<<<OUT_FEAT / 64, 256, 0, stream>>>(partials, out);
}